// Round 4
// baseline (262.347 us; speedup 1.0000x reference)
//
#include <hip/hip_runtime.h>
#include <math.h>

#define NPT 2048
#define KNN 20

typedef const float* fp;

// ---------------------------------------------------------------------------
// k0: zero the BN stats buffer (512 floats) — capture-safe replacement for
//     hipMemsetAsync.
// ---------------------------------------------------------------------------
__global__ void k0_zero(float* stats) { stats[threadIdx.x] = 0.0f; }

// ---------------------------------------------------------------------------
// k1: per 16 points — stage x to LDS, emit xx (sum of squares) and
//     q/k/v = Wx + b in point-major [p][c] f32 layout.
// ---------------------------------------------------------------------------
__global__ __launch_bounds__(256) void k1_qkv(
    fp xbf, fp wq, fp wk, fp wv, fp bq, fp bk, fp bv,
    float* qT, float* kT, float* vT, float* xx) {
    __shared__ float xs[16][129];          // [point][chan], +1 pad
    int t = threadIdx.x;
    int p0 = blockIdx.x * 16;
    int b = p0 >> 11, n0 = p0 & 2047;
    fp xb = xbf + (size_t)b * 128 * NPT;

    {   // stage: thread t loads 8 consecutive n of channel c
        int c = t >> 1, half = t & 1;
        float4 f0 = *reinterpret_cast<const float4*>(xb + (size_t)c * NPT + n0 + half * 8);
        float4 f1 = *reinterpret_cast<const float4*>(xb + (size_t)c * NPT + n0 + half * 8 + 4);
        xs[half * 8 + 0][c] = f0.x; xs[half * 8 + 1][c] = f0.y;
        xs[half * 8 + 2][c] = f0.z; xs[half * 8 + 3][c] = f0.w;
        xs[half * 8 + 4][c] = f1.x; xs[half * 8 + 5][c] = f1.y;
        xs[half * 8 + 6][c] = f1.z; xs[half * 8 + 7][c] = f1.w;
    }
    __syncthreads();

    if (t < 16) {
        float s = 0.f;
        for (int c = 0; c < 128; c++) { float v = xs[t][c]; s += v * v; }
        xx[p0 + t] = s;
    }

    int o = t & 127, pg = t >> 7;          // out-channel, point-group (0/1)
    float aq[8], ak[8], av[8];
    #pragma unroll
    for (int k = 0; k < 8; k++) { aq[k] = 0.f; ak[k] = 0.f; av[k] = 0.f; }
    for (int i = 0; i < 128; i += 4) {
        float4 fq = *reinterpret_cast<const float4*>(wq + o * 128 + i);
        float4 fk = *reinterpret_cast<const float4*>(wk + o * 128 + i);
        float4 fv = *reinterpret_cast<const float4*>(wv + o * 128 + i);
        float wqv[4] = {fq.x, fq.y, fq.z, fq.w};
        float wkv[4] = {fk.x, fk.y, fk.z, fk.w};
        float wvv[4] = {fv.x, fv.y, fv.z, fv.w};
        #pragma unroll
        for (int ii = 0; ii < 4; ii++) {
            #pragma unroll
            for (int k = 0; k < 8; k++) {
                float xv = xs[pg * 8 + k][i + ii];
                aq[k] += wqv[ii] * xv; ak[k] += wkv[ii] * xv; av[k] += wvv[ii] * xv;
            }
        }
    }
    float bqv = bq[o], bkv = bk[o], bvv = bv[o];
    #pragma unroll
    for (int k = 0; k < 8; k++) {
        size_t row = (size_t)(p0 + pg * 8 + k) * 128 + o;
        qT[row] = aq[k] + bqv;
        kT[row] = ak[k] + bkv;
        vT[row] = av[k] + bvv;
    }
}

// ---------------------------------------------------------------------------
// k2: 4 pd rows per block + register-resident top-20.
// pd[n][m] = 2*dot(x_n,x_m) - xx[n] - xx[m]; tie-break = lowest index (jax).
// ---------------------------------------------------------------------------
#define MERGE(off) { float ov = __shfl_xor(bv, off); int oi = __shfl_xor(bi, off); \
                     if (ov > bv || (ov == bv && oi < bi)) { bv = ov; bi = oi; } }

__global__ __launch_bounds__(256) void k2_pd_topk(
    fp xbf, const float* xx, int* idxbuf) {
    __shared__ float pds[4][2048];
    __shared__ float xnl[4][128];
    __shared__ float xxs[4];
    int t = threadIdx.x;
    int r0 = blockIdx.x * 4;
    int b = r0 >> 11, nloc = r0 & 2047;
    fp xb = xbf + (size_t)b * 128 * NPT;

    for (int rr = 0; rr < 2; rr++) {
        int row = rr * 2 + (t >> 7), c = t & 127;
        xnl[row][c] = xb[c * NPT + nloc + row];
    }
    if (t < 4) xxs[t] = xx[r0 + t];
    __syncthreads();

    float acc[4][8];
    #pragma unroll
    for (int r = 0; r < 4; r++)
        #pragma unroll
        for (int j = 0; j < 8; j++) acc[r][j] = 0.f;

    for (int c = 0; c < 128; c++) {
        float4 f0 = *reinterpret_cast<const float4*>(xb + (size_t)c * NPT + t * 8);
        float4 f1 = *reinterpret_cast<const float4*>(xb + (size_t)c * NPT + t * 8 + 4);
        float xc[8] = {f0.x, f0.y, f0.z, f0.w, f1.x, f1.y, f1.z, f1.w};
        float xn0 = xnl[0][c], xn1 = xnl[1][c], xn2 = xnl[2][c], xn3 = xnl[3][c];
        #pragma unroll
        for (int j = 0; j < 8; j++) {
            acc[0][j] += xn0 * xc[j];
            acc[1][j] += xn1 * xc[j];
            acc[2][j] += xn2 * xc[j];
            acc[3][j] += xn3 * xc[j];
        }
    }
    float4 xxa = *reinterpret_cast<const float4*>(xx + b * NPT + t * 8);
    float4 xxb = *reinterpret_cast<const float4*>(xx + b * NPT + t * 8 + 4);
    float xxm[8] = {xxa.x, xxa.y, xxa.z, xxa.w, xxb.x, xxb.y, xxb.z, xxb.w};
    #pragma unroll
    for (int r = 0; r < 4; r++)
        #pragma unroll
        for (int j = 0; j < 8; j++)
            pds[r][t * 8 + j] = 2.0f * acc[r][j] - xxs[r] - xxm[j];
    __syncthreads();

    // top-20, one wave per row: candidates in registers, removal via bitmask
    int row = t >> 6, lane = t & 63;
    float rv[32];
    #pragma unroll
    for (int q = 0; q < 32; q++) rv[q] = pds[row][lane + (q << 6)];
    unsigned removed = 0;
    for (int iter = 0; iter < KNN; iter++) {
        float bv = -3.4e38f; int bi = 0;
        #pragma unroll
        for (int q = 0; q < 32; q++) {
            bool live = ((removed >> q) & 1u) == 0u;
            if (live && rv[q] > bv) { bv = rv[q]; bi = lane + (q << 6); }
        }
        MERGE(32) MERGE(16) MERGE(8) MERGE(4) MERGE(2) MERGE(1)
        bi &= 2047;                                          // defensive clamp
        if (lane == 0) idxbuf[(size_t)(r0 + row) * KNN + iter] = bi;
        if ((bi & 63) == lane) removed |= 1u << (bi >> 6);   // owner masks slot
    }
}

// ---------------------------------------------------------------------------
// k3: sparse mutual-KNN attention. 128 threads = one point, t = h*32 + d.
// Mutuality: n appears in idxbuf[m] (20-entry scan, block-uniform).
// ---------------------------------------------------------------------------
__global__ __launch_bounds__(128) void k3_attn(
    fp qT, fp kT, fp vT, const int* idxbuf, float* avT) {
    __shared__ float sbuf[KNN * 4];
    __shared__ int   mlist[KNN];
    int t = threadIdx.x;
    int p = blockIdx.x;
    int b = p >> 11, n = p & 2047;
    int h = t >> 5;
    float qv = qT[(size_t)p * 128 + t];

    int cnt = 0;
    for (int j = 0; j < KNN; j++) {
        int m = idxbuf[(size_t)p * KNN + j] & 2047;         // block-uniform
        const int* mrow = idxbuf + (size_t)(b * NPT + m) * KNN;
        bool mut = false;
        for (int jj = 0; jj < KNN; jj++) mut = mut || (mrow[jj] == n);
        if (mut) {                                          // uniform branch
            float prod = qv * kT[(size_t)(b * NPT + m) * 128 + t];
            prod += __shfl_xor(prod, 16);
            prod += __shfl_xor(prod, 8);
            prod += __shfl_xor(prod, 4);
            prod += __shfl_xor(prod, 2);
            prod += __shfl_xor(prod, 1);
            if ((t & 31) == 0) sbuf[cnt * 4 + h] = prod * 0.17677669529663687f;
            if (t == 0) mlist[cnt] = m;
            cnt++;
        }
    }
    __syncthreads();

    float mx = -3.4e38f;
    for (int j = 0; j < cnt; j++) mx = fmaxf(mx, sbuf[j * 4 + h]);
    float den = 0.f;
    for (int j = 0; j < cnt; j++) den += expf(sbuf[j * 4 + h] - mx);
    float inv = (cnt > 0) ? (1.0f / den) : 0.0f;
    float acc = 0.f;
    for (int j = 0; j < cnt; j++) {
        float pw = expf(sbuf[j * 4 + h] - mx) * inv;
        acc += pw * vT[(size_t)(b * NPT + mlist[j]) * 128 + t];
    }
    avT[(size_t)p * 128 + t] = acc;
}

// ---------------------------------------------------------------------------
// k4: avm = wm@av + bm; h = w1@[x; avm] + b1; BN partial sums (atomics).
// ---------------------------------------------------------------------------
__global__ __launch_bounds__(256) void k4_h(
    fp xbf, const float* avT, fp wm, fp bm, fp w1, fp b1,
    float* hbuf, float* stats) {
    __shared__ float avs[16][128];
    __shared__ float cvec[16][256];
    int t = threadIdx.x;
    int p0 = blockIdx.x * 16;
    int b = p0 >> 11, n0 = p0 & 2047;
    fp xb = xbf + (size_t)b * 128 * NPT;

    for (int r = 0; r < 8; r++) {
        int e = t + 256 * r;
        int p = e >> 7, c = e & 127;
        avs[p][c] = avT[(size_t)(p0 + p) * 128 + c];
    }
    {   // x part of cvec, cols 0..127
        int c = t >> 1, half = t & 1;
        float4 f0 = *reinterpret_cast<const float4*>(xb + (size_t)c * NPT + n0 + half * 8);
        float4 f1 = *reinterpret_cast<const float4*>(xb + (size_t)c * NPT + n0 + half * 8 + 4);
        cvec[half * 8 + 0][c] = f0.x; cvec[half * 8 + 1][c] = f0.y;
        cvec[half * 8 + 2][c] = f0.z; cvec[half * 8 + 3][c] = f0.w;
        cvec[half * 8 + 4][c] = f1.x; cvec[half * 8 + 5][c] = f1.y;
        cvec[half * 8 + 6][c] = f1.z; cvec[half * 8 + 7][c] = f1.w;
    }
    __syncthreads();

    int o = t & 127, pg = t >> 7;
    float am[8];
    #pragma unroll
    for (int k = 0; k < 8; k++) am[k] = 0.f;
    for (int i = 0; i < 128; i += 4) {
        float4 fw = *reinterpret_cast<const float4*>(wm + o * 128 + i);
        float wv[4] = {fw.x, fw.y, fw.z, fw.w};
        #pragma unroll
        for (int ii = 0; ii < 4; ii++)
            #pragma unroll
            for (int k = 0; k < 8; k++)
                am[k] += wv[ii] * avs[pg * 8 + k][i + ii];
    }
    float bmv = bm[o];
    #pragma unroll
    for (int k = 0; k < 8; k++) cvec[pg * 8 + k][128 + o] = am[k] + bmv;
    __syncthreads();

    float hh[16];
    #pragma unroll
    for (int p = 0; p < 16; p++) hh[p] = 0.f;
    for (int i = 0; i < 256; i += 4) {
        float4 fw = *reinterpret_cast<const float4*>(w1 + t * 256 + i);
        float wv[4] = {fw.x, fw.y, fw.z, fw.w};
        #pragma unroll
        for (int ii = 0; ii < 4; ii++)
            #pragma unroll
            for (int p = 0; p < 16; p++)
                hh[p] += wv[ii] * cvec[p][i + ii];
    }
    float b1v = b1[t];
    float s = 0.f, s2 = 0.f;
    for (int p = 0; p < 16; p++) {
        float v = hh[p] + b1v;
        hbuf[(size_t)(p0 + p) * 256 + t] = v;
        s += v; s2 += v * v;
    }
    atomicAdd(&stats[t], s);
    atomicAdd(&stats[256 + t], s2);
}

// ---------------------------------------------------------------------------
// k5: BN + ReLU + w2 conv + residual -> f32 out (B,C,N,1).
// ---------------------------------------------------------------------------
__global__ __launch_bounds__(256) void k5_out(
    const float* hbuf, const float* stats, fp gamma, fp beta,
    fp w2, fp b2, fp xbf, float* out) {
    __shared__ float hn[16][256];
    int t = threadIdx.x;
    int p0 = blockIdx.x * 16;
    int b = p0 >> 11, n0 = p0 & 2047;

    float mu  = stats[t] * (1.0f / 4096.0f);
    float var = stats[256 + t] * (1.0f / 4096.0f) - mu * mu;
    var = fmaxf(var, 0.0f);
    float a    = gamma[t] / sqrtf(var + 1e-5f);
    float cadd = beta[t] - mu * a;
    for (int r = 0; r < 16; r++) {
        float v = hbuf[(size_t)(p0 + r) * 256 + t] * a + cadd;
        hn[r][t] = fmaxf(v, 0.0f);
    }
    __syncthreads();

    int o = t & 127, pg = t >> 7;
    float acc[8];
    #pragma unroll
    for (int k = 0; k < 8; k++) acc[k] = 0.f;
    for (int i = 0; i < 256; i += 4) {
        float4 fw = *reinterpret_cast<const float4*>(w2 + o * 256 + i);
        float wv[4] = {fw.x, fw.y, fw.z, fw.w};
        #pragma unroll
        for (int ii = 0; ii < 4; ii++)
            #pragma unroll
            for (int k = 0; k < 8; k++)
                acc[k] += wv[ii] * hn[pg * 8 + k][i + ii];
    }
    fp xb = xbf + (size_t)b * 128 * NPT;
    float4 x0 = *reinterpret_cast<const float4*>(xb + (size_t)o * NPT + n0 + pg * 8);
    float4 x1 = *reinterpret_cast<const float4*>(xb + (size_t)o * NPT + n0 + pg * 8 + 4);
    float xv[8] = {x0.x, x0.y, x0.z, x0.w, x1.x, x1.y, x1.z, x1.w};

    float b2v = b2[o];
    float4 o0, o1;
    o0.x = acc[0] + b2v + xv[0]; o0.y = acc[1] + b2v + xv[1];
    o0.z = acc[2] + b2v + xv[2]; o0.w = acc[3] + b2v + xv[3];
    o1.x = acc[4] + b2v + xv[4]; o1.y = acc[5] + b2v + xv[5];
    o1.z = acc[6] + b2v + xv[6]; o1.w = acc[7] + b2v + xv[7];
    size_t base = (size_t)b * 128 * NPT + (size_t)o * NPT + n0 + pg * 8;
    *reinterpret_cast<float4*>(out + base)     = o0;
    *reinterpret_cast<float4*>(out + base + 4) = o1;
}

// ---------------------------------------------------------------------------
// Workspace layout (8,734,720 bytes), all f32:
//   0        qT   2MB  [k1->k3]   <- hbuf (4MB, k4->k5) aliases qT+kT
//   2097152  kT   2MB  [k1->k3]
//   4194304  vT   2MB  [k1->k3]
//   6291456  avT  2MB  [k3->k4]
//   8388608  xx   16KB [k1->k2]
//   8404992  idxb 320KB[k2->k3]
//   8732672  stats 2KB [k0->k5]
// ---------------------------------------------------------------------------
#define WS_NEEDED 8734720u

extern "C" void kernel_launch(void* const* d_in, const int* in_sizes, int n_in,
                              void* d_out, int out_size, void* d_ws, size_t ws_size,
                              hipStream_t stream) {
    fp desc1 = (fp)d_in[0];
    fp wq = (fp)d_in[1];  fp bq = (fp)d_in[2];
    fp wk = (fp)d_in[3];  fp bk = (fp)d_in[4];
    fp wv = (fp)d_in[5];  fp bv = (fp)d_in[6];
    fp wm = (fp)d_in[7];  fp bm = (fp)d_in[8];
    fp w1 = (fp)d_in[9];  fp b1 = (fp)d_in[10];
    fp gamma = (fp)d_in[11]; fp beta = (fp)d_in[12];
    fp w2 = (fp)d_in[13]; fp b2 = (fp)d_in[14];

    if (ws_size < (size_t)WS_NEEDED) return;   // zero output => ws too small

    char* ws = (char*)d_ws;
    float* qT    = (float*)(ws + 0);
    float* kT    = (float*)(ws + 2097152);
    float* vT    = (float*)(ws + 4194304);
    float* avT   = (float*)(ws + 6291456);
    float* xx    = (float*)(ws + 8388608);
    int*   idxb  = (int*)  (ws + 8404992);
    float* stats = (float*)(ws + 8732672);
    float* hbuf  = (float*)(ws + 0);           // aliases qT+kT (dead after k3)

    k0_zero<<<1, 512, 0, stream>>>(stats);
    k1_qkv<<<256, 256, 0, stream>>>(desc1, wq, wk, wv, bq, bk, bv, qT, kT, vT, xx);
    k2_pd_topk<<<1024, 256, 0, stream>>>(desc1, xx, idxb);
    k3_attn<<<4096, 128, 0, stream>>>(qT, kT, vT, idxb, avT);
    k4_h<<<256, 256, 0, stream>>>(desc1, avT, wm, bm, w1, b1, hbuf, stats);
    k5_out<<<256, 256, 0, stream>>>(hbuf, stats, gamma, beta, w2, b2, desc1,
                                    (float*)d_out);
}